// Round 12
// baseline (463.425 us; speedup 1.0000x reference)
//
#include <hip/hip_runtime.h>
#include <cstdint>
#include <cstddef>

#define BN_EPS 1e-5

// ---------------- R12 = R11 + conv2/conv3 split into half-batch dispatches ----
// Diagnostic: top-5 only ever shows the single slowest kernel (5 rows = 5
// bench reps). conv2@78 masks everything below it; the unexplained budget is
// ~320us across 13 never-observed kernels. Halving conv2/conv3 (each half
// ~25-40us) forces any hidden kernel >=40us into the next top-5.
// Also: conv2 waves_per_eu max 4->8 (VGPR 56 allows 8 waves/SIMD).

// one mega-kernel for all weight packing + zeroing (input-independent).
__global__ void pack_weights_all(const float* __restrict__ cw0, const float* __restrict__ cw1,
                                 const float* __restrict__ cw2, const float* __restrict__ fw0,
                                 const float* __restrict__ fw1,
                                 uint32_t* __restrict__ wm1, uint64_t* __restrict__ w1p,
                                 uint64_t* __restrict__ w2p, uint64_t* __restrict__ w3p,
                                 uint64_t* __restrict__ w4p, double* __restrict__ zp, int zn) {
  int bb = blockIdx.x, t = threadIdx.x, lane = t & 63, wv = t >> 6;
  if (bb == 0) {
    if (t < 128) {
      uint32_t m = 0;
      for (int j = 0; j < 27; j++) m |= (uint32_t)(cw0[t * 27 + j] > 0.f) << j;
      wm1[t] = m;
    }
  } else if (bb < 19) {          // conv2 weights: 256*9*2 = 4608 items
    int i = (bb - 1) * 256 + t;
    if (i < 4608) {
      int wd = i % 2, t2 = i / 2, tap = t2 % 9, co = t2 / 9;
      uint64_t bits = 0;
      for (int k = 0; k < 64; k++)
        bits |= (uint64_t)(cw1[((long)co * 128 + wd * 64 + k) * 9 + tap] > 0.f) << k;
      w1p[i] = bits;
    }
  } else if (bb < 91) {          // conv3 weights: 512*9*4 = 18432 items
    int i = (bb - 19) * 256 + t;
    if (i < 18432) {
      int wd = i % 4, t2 = i / 4, tap = t2 % 9, co = t2 / 9;
      uint64_t bits = 0;
      for (int k = 0; k < 64; k++)
        bits |= (uint64_t)(cw2[((long)co * 256 + wd * 64 + k) * 9 + tap] > 0.f) << k;
      w2p[i] = bits;
    }
  } else if (bb < 9307) {        // fc0 weights transposed: 1024*288 = 294912 wids
    long base = ((long)(bb - 91) * 4 + wv) * 8;
    for (int j = 0; j < 8; j++) {
      long wid = base + j;
      if (wid >= 294912) break;
      long o = wid / 288;
      int wd = (int)(wid % 288);
      uint64_t m = __ballot(fw0[o * 18432 + wd * 64 + lane] > 0.f);
      if (lane == 0) w3p[(long)wd * 1024 + o] = m;
    }
  } else if (bb < 9312) {        // fc1 weights transposed: 160 wids
    long base = ((long)(bb - 9307) * 4 + wv) * 8;
    for (int j = 0; j < 8; j++) {
      long wid = base + j;
      if (wid >= 160) break;
      long o = wid / 16;
      int wd = (int)(wid % 16);
      uint64_t m = __ballot(fw1[o * 1024 + wd * 64 + lane] > 0.f);
      if (lane == 0) w4p[(long)wd * 10 + o] = m;
    }
  } else {                       // zero fc0 atomic stats region
    int i = (bb - 9312) * 256 + t;
    if (i < zn) zp[i] = 0.0;
  }
}

// one contiguous HW plane per block: grid (C, N); partial per (c,n)
__global__ void reduce_plane_p(const float* __restrict__ x, double* __restrict__ pp,
                               int C, int HW) {
  int c = blockIdx.x, n = blockIdx.y;
  const float* p = x + ((long)n * C + c) * HW;
  double s = 0.0, s2 = 0.0;
  for (int i = threadIdx.x; i < HW; i += blockDim.x) {
    double v = (double)p[i];
    s += v; s2 += v * v;
  }
  for (int o = 32; o > 0; o >>= 1) {
    s  += __shfl_down(s, o, 64);
    s2 += __shfl_down(s2, o, 64);
  }
  __shared__ double ls[4], ls2[4];
  int lane = threadIdx.x & 63, w = threadIdx.x >> 6;
  if (lane == 0) { ls[w] = s; ls2[w] = s2; }
  __syncthreads();
  if (threadIdx.x == 0) {
    double a = 0, b = 0;
    for (int i = 0; i < 4; i++) { a += ls[i]; b += ls2[i]; }
    long o = ((long)n * C + c) * 2;
    pp[o] = a; pp[o + 1] = b;
  }
}

// pack x signs; finalize_plane fused in-block.
__global__ void pack_bits_c1_f(const float* __restrict__ x, const double* __restrict__ pplane,
                               const float* __restrict__ g, const float* __restrict__ b,
                               uint64_t* __restrict__ rows, int nwid) {
  __shared__ double2 stc[3];
  int t = threadIdx.x, lane = t & 63, wv = t >> 6;
  if (wv < 3) {
    int c = wv;
    double s  = pplane[((long)lane * 3 + c) * 2]     + pplane[((long)(lane + 64) * 3 + c) * 2];
    double s2 = pplane[((long)lane * 3 + c) * 2 + 1] + pplane[((long)(lane + 64) * 3 + c) * 2 + 1];
    for (int o = 32; o > 0; o >>= 1) {
      s  += __shfl_down(s, o, 64);
      s2 += __shfl_down(s2, o, 64);
    }
    if (lane == 0) {
      double m = s / 524288.0;
      double v = s2 / 524288.0 - m * m;
      stc[c] = make_double2(m, 1.0 / sqrt(v + BN_EPS));
    }
  }
  __syncthreads();
  long base = ((long)blockIdx.x * 4 + wv) * 8;
  for (int j = 0; j < 8; j++) {
    long wid = base + j;
    if (wid >= nwid) return;
    int n = (int)(wid / 192), rem = (int)(wid % 192);
    int ci = rem >> 6, y = rem & 63;
    double2 s = stc[ci];
    float xv = x[(((long)n * 3 + ci) * 64 + y) * 64 + lane];
    float xn = (float)(((double)xv - s.x) * s.y) * g[ci] + b[ci];
    uint64_t m = __ballot(xn > 0.f);
    if (lane == 0) rows[wid] = m;
  }
}

// finalize conv-fused partials, layout pp[y][C]: block per channel.
__global__ void finalize_pp1(const double2* __restrict__ pp, double2* __restrict__ st,
                             int C, int Y, double cnt) {
  int c = blockIdx.x;
  double s = 0.0, s2 = 0.0;
  for (int y = threadIdx.x; y < Y; y += blockDim.x) {
    double2 p = pp[(long)y * C + c];
    s += p.x; s2 += p.y;
  }
  for (int o = 32; o > 0; o >>= 1) {
    s  += __shfl_down(s, o, 64);
    s2 += __shfl_down(s2, o, 64);
  }
  __shared__ double ls[4], ls2[4];
  int lane = threadIdx.x & 63, w = threadIdx.x >> 6;
  if (lane == 0) { ls[w] = s; ls2[w] = s2; }
  __syncthreads();
  if (threadIdx.x == 0) {
    double a = ls[0] + ls[1] + ls[2] + ls[3];
    double b = ls2[0] + ls2[1] + ls2[2] + ls2[3];
    double m = a / cnt;
    double v = b / cnt - m * m;
    st[c] = make_double2(m, 1.0 / sqrt(v + BN_EPS));
  }
}

// finalize conv2 partials: pp[bid][64] with bid = n*16 + (cg*4+chunk).
__global__ void finalize_pp2(const double2* __restrict__ pp, double2* __restrict__ st,
                             double cnt) {
  int c = blockIdx.x;
  int cg = c >> 6, l = c & 63;
  double s = 0.0, s2 = 0.0;
  for (int y = threadIdx.x; y < 512; y += blockDim.x) {
    int n = y >> 2, ch = y & 3;
    double2 p = pp[(long)(n * 16 + cg * 4 + ch) * 64 + l];
    s += p.x; s2 += p.y;
  }
  for (int o = 32; o > 0; o >>= 1) {
    s  += __shfl_down(s, o, 64);
    s2 += __shfl_down(s2, o, 64);
  }
  __shared__ double ls[4], ls2[4];
  int lane = threadIdx.x & 63, w = threadIdx.x >> 6;
  if (lane == 0) { ls[w] = s; ls2[w] = s2; }
  __syncthreads();
  if (threadIdx.x == 0) {
    double a = ls[0] + ls[1] + ls[2] + ls[3];
    double b = ls2[0] + ls2[1] + ls2[2] + ls2[3];
    double m = a / cnt;
    double v = b / cnt - m * m;
    st[c] = make_double2(m, 1.0 / sqrt(v + BN_EPS));
  }
}

// per-feature reduce of a3 (i16 dots, prelu inline); depth-8 atomics.
__global__ void reduce_cols2_i16(const short* __restrict__ x, const float* __restrict__ cp,
                                 double* __restrict__ sums, int R, int F, int RS) {
  int f = blockIdx.x * blockDim.x + threadIdx.x;
  int r0 = blockIdx.y * RS, r1 = min(r0 + RS, R);
  float alpha = cp[0];
  double s = 0.0, s2 = 0.0;
  for (int r = r0; r < r1; r++) {
    int xi = x[(long)r * F + f];
    float pr = xi >= 0 ? (float)xi : alpha * (float)xi;
    double v = (double)pr;
    s += v; s2 += v * v;
  }
  atomicAdd(&sums[2 * f], s);
  atomicAdd(&sums[2 * f + 1], s2);
}

// ---------------- activation pack kernels ----------------

__global__ void pack_cl_i8(const signed char* __restrict__ acl, const double2* __restrict__ st,
                           const float* __restrict__ g, const float* __restrict__ b,
                           const float* __restrict__ cp, uint64_t* __restrict__ out,
                           int C, long nwords, int lw) {
  long base = ((long)blockIdx.x * 4 + (threadIdx.x >> 6)) * 8;
  int lane = threadIdx.x & 63;
  float alpha = cp[0];
  for (int j = 0; j < 8; j++) {
    long wid = base + j;
    if (wid >= nwords) return;
    long row = wid >> lw;
    int w = (int)(wid & ((1 << lw) - 1));
    int c = w * 64 + lane;
    double2 s = st[c];
    int xi = acl[row * C + c];
    float pr = xi >= 0 ? (float)xi : alpha * (float)xi;
    float xn = (float)(((double)pr - s.x) * s.y) * g[c] + b[c];
    uint64_t m = __ballot(xn > 0.f);
    if (lane == 0) out[wid] = m;
  }
}

__global__ void pack_cl_i16(const short* __restrict__ acl, const double2* __restrict__ st,
                            const float* __restrict__ g, const float* __restrict__ b,
                            const float* __restrict__ cp, uint64_t* __restrict__ out,
                            int C, long nwords, int lw) {
  long base = ((long)blockIdx.x * 4 + (threadIdx.x >> 6)) * 8;
  int lane = threadIdx.x & 63;
  float alpha = cp[0];
  for (int j = 0; j < 8; j++) {
    long wid = base + j;
    if (wid >= nwords) return;
    long row = wid >> lw;
    int w = (int)(wid & ((1 << lw) - 1));
    int c = w * 64 + lane;
    double2 s = st[c];
    int xi = acl[row * C + c];
    float pr = xi >= 0 ? (float)xi : alpha * (float)xi;
    float xn = (float)(((double)pr - s.x) * s.y) * g[c] + b[c];
    uint64_t m = __ballot(xn > 0.f);
    if (lane == 0) out[wid] = m;
  }
}

// pack sign+nz masks from a3 with finalize_stats INLINED (m,rs from sums).
__global__ void pack_nz_st_i16(const short* __restrict__ x, const double* __restrict__ sums,
                               const float* __restrict__ g, const float* __restrict__ b,
                               const float* __restrict__ cp, uint64_t* __restrict__ out,
                               int R, int F) {
  int Wf = F >> 6;
  long base = ((long)blockIdx.x * 4 + (threadIdx.x >> 6)) * 8;
  int lane = threadIdx.x & 63;
  float alpha = cp[0];
  for (int j = 0; j < 8; j++) {
    long wid = base + j;
    if (wid >= (long)R * Wf) return;
    long r = wid / Wf;
    int w = (int)(wid % Wf);
    int f = w * 64 + lane;
    double m = sums[2 * f] / 128.0;
    double v = sums[2 * f + 1] / 128.0 - m * m;
    double rs = 1.0 / sqrt(v + BN_EPS);
    int xi = x[r * F + f];
    float pr = xi >= 0 ? (float)xi : alpha * (float)xi;
    double d = (double)pr - m;  // exact for lattice values
    float xn = (float)(d * rs) * g[f] + b[f];
    uint64_t sm = __ballot(xn > 0.f);
    uint64_t nm = __ballot(d != 0.0);
    if (lane == 0) { out[2 * wid] = sm; out[2 * wid + 1] = nm; }
  }
}

// ---------------- fused conv + maxpool + prelu (+ BN stats) ----------------

// conv1: i8 dots channel-last [n][961][128] + fused per-block stats.
__global__ __launch_bounds__(256) void conv1_pool3_i8(const uint64_t* __restrict__ rows,
                                                      const uint32_t* __restrict__ wm,
                                                      const float* __restrict__ cp,
                                                      signed char* __restrict__ out,
                                                      double2* __restrict__ pp) {
  __shared__ uint64_t rL[192];
  __shared__ uint32_t wL[128];
  __shared__ uint32_t mL[61 * 4];
  __shared__ double2 sm[256];
  int n = blockIdx.y, chunk = blockIdx.x, t = threadIdx.x;
  if (t < 192) rL[t] = rows[n * 192 + t];
  if (t < 128) wL[t] = wm[t];
  __syncthreads();
  if (t < 244) {
    int pl = t >> 2, quad = t & 3;
    int pos = chunk * 61 + pl;
    if (pos < 961) {
      int py = pos / 31, px = pos - py * 31;
      int cy = 2 * py + (quad >> 1), cx = 2 * px + (quad & 1);
      uint32_t m = 0;
#pragma unroll
      for (int ci = 0; ci < 3; ci++)
#pragma unroll
        for (int ky = 0; ky < 3; ky++)
          m |= (uint32_t)((rL[ci * 64 + cy + ky] >> cx) & 7) << (ci * 9 + ky * 3);
      mL[pl * 4 + quad] = m;
    }
  }
  __syncthreads();
  int co = t & 127, slot = t >> 7;
  float alpha = cp[0];
  uint32_t w = wL[co];
  double s = 0.0, s2 = 0.0;
  for (int i = slot; i < 61; i += 2) {
    int pos = chunk * 61 + i;
    if (pos >= 961) break;
    int p0 = __popc(mL[4 * i] ^ w);
    int p1 = __popc(mL[4 * i + 1] ^ w);
    int p2 = __popc(mL[4 * i + 2] ^ w);
    int p3 = __popc(mL[4 * i + 3] ^ w);
    int dot = 27 - 2 * min(min(p0, p1), min(p2, p3));
    out[((long)n * 961 + pos) * 128 + co] = (signed char)dot;
    float pr = dot >= 0 ? (float)dot : alpha * (float)dot;
    double v = (double)pr;
    s += v; s2 += v * v;
  }
  sm[t] = make_double2(s, s2);
  __syncthreads();
  if (t < 128) {
    double2 a = sm[t], b = sm[t + 128];
    pp[((long)n * 16 + chunk) * 128 + t] = make_double2(a.x + b.x, a.y + b.y);
  }
}

// conv2: i16 dots CL [n][196][256] + fused stats. n = blockIdx.y + n0 so the
// grid can be split into half-batch dispatches (R12 diagnostic). waves_per_eu
// max 4->8: VGPR=56 allows 8 waves/SIMD; LDS 9216*8 blocks = 74KB < 160KB.
template <int W, int IH, int PH, int CHUNK>
__global__ __attribute__((amdgpu_flat_work_group_size(256, 256),
                          amdgpu_waves_per_eu(3, 8)))
void convp_carry_i16(const uint64_t* __restrict__ in, const uint64_t* __restrict__ wt,
                     const float* __restrict__ cp, short* __restrict__ out,
                     double2* __restrict__ pp, int CO, int n0) {
  __shared__ uint64_t sIn[10 * IH * W];
  __shared__ double2 sm[256];
  int n = blockIdx.y + n0;
  int cg = blockIdx.x / CHUNK, chunk = blockIdx.x % CHUNK;
  int t = threadIdx.x, lane = t & 63, slot = t >> 6;
  int r0 = chunk * 8;
  int nr = min(10, IH - r0);
  const uint64_t* src = in + ((long)n * IH + r0) * (IH * W);
  for (int i = t; i < nr * IH * W; i += 256) sIn[i] = src[i];
  int co = cg * 64 + lane;
  uint64_t wr[9 * W];
  const uint64_t* wg = wt + (long)co * (9 * W);
#pragma unroll
  for (int i = 0; i < 9 * W; i++) wr[i] = wg[i];
  __syncthreads();
  int py = chunk * 4 + slot;
  float alpha = cp[0];
  double s = 0.0, s2 = 0.0;
  if (py < PH) {
    const int K = 9 * 64 * W;
    const uint64_t* base = &sIn[(2 * slot) * (IH * W)];
    uint64_t c[4][2 * W];
#pragma unroll
    for (int cy = 0; cy < 4; cy++) {
      const uint64_t* p = &base[(cy * IH) * W];
#pragma unroll
      for (int j = 0; j < 2 * W; j++) c[cy][j] = p[j];
    }
#pragma unroll
    for (int px = 0; px < PH; px++) {
      int a00 = 0, a01 = 0, a10 = 0, a11 = 0;
#pragma unroll
      for (int cy = 0; cy < 4; cy++) {
        uint64_t f[2 * W];
        const uint64_t* fp = &base[(cy * IH + 2 * px + 2) * W];
#pragma unroll
        for (int j = 0; j < 2 * W; j++) f[j] = fp[j];
#pragma unroll
        for (int col = 0; col < 4; col++) {
#pragma unroll
          for (int wd = 0; wd < W; wd++) {
            uint64_t v = (col < 2) ? c[cy][col * W + wd] : f[(col - 2) * W + wd];
#pragma unroll
            for (int dy = 0; dy < 2; dy++) {
              int ky = cy - dy;
              if (ky < 0 || ky > 2) continue;
#pragma unroll
              for (int dx = 0; dx < 2; dx++) {
                int kx = col - dx;
                if (kx < 0 || kx > 2) continue;
                int p = __popcll(v ^ wr[(ky * 3 + kx) * W + wd]);
                if (dy == 0) { if (dx == 0) a00 += p; else a01 += p; }
                else         { if (dx == 0) a10 += p; else a11 += p; }
              }
            }
          }
        }
#pragma unroll
        for (int j = 0; j < 2 * W; j++) c[cy][j] = f[j];
      }
      int dot = K - 2 * min(min(a00, a01), min(a10, a11));
      out[((long)n * PH * PH + py * PH + px) * CO + co] = (short)dot;
      float pr = dot >= 0 ? (float)dot : alpha * (float)dot;
      double v = (double)pr;
      s += v; s2 += v * v;
    }
  }
  sm[t] = make_double2(s, s2);
  __syncthreads();
  if (t < 64) {
    double2 a = sm[t], b = sm[64 + t], cc = sm[128 + t], d = sm[192 + t];
    pp[((long)n * 16 + blockIdx.x) * 64 + t] =
        make_double2(a.x + b.x + cc.x + d.x, a.y + b.y + cc.y + d.y);
  }
}

// conv3: i16 dots channel-major [n][512][36]; n = blockIdx.y + n0 (split).
#define TAP2(acc, P, wa, wb) acc += __popcll((P).x ^ (wa)) + __popcll((P).y ^ (wb));
#define ROWT(aL, aR, pA, pB, pC, pD, WX, WY, WZ)                \
  TAP2(aL, pA, WX.x, WX.y) TAP2(aL, pB, WY.x, WY.y)             \
  TAP2(aL, pC, WZ.x, WZ.y)                                      \
  TAP2(aR, pB, WX.x, WX.y) TAP2(aR, pC, WY.x, WY.y)             \
  TAP2(aR, pD, WZ.x, WZ.y)

__global__ __attribute__((amdgpu_flat_work_group_size(256, 256),
                          amdgpu_waves_per_eu(4, 6)))
void convs3_i16(const uint64_t* __restrict__ in, const uint64_t* __restrict__ wt,
                short* __restrict__ out, int n0) {
  __shared__ uint64_t sIn[14 * 14 * 4];
  int n = blockIdx.y + n0, cg = blockIdx.x;
  int t = threadIdx.x, lane = t & 63, slot = t >> 6;
  const uint64_t* src = in + (long)n * 784;
  for (int i = t; i < 784; i += 256) sIn[i] = src[i];
  int h = lane >> 5;
  int co = cg * 32 + (lane & 31);
  const uint64_t* wg = wt + co * 36 + 2 * h;
  ulonglong2 W0 = *(const ulonglong2*)(wg + 0);
  ulonglong2 W1 = *(const ulonglong2*)(wg + 4);
  ulonglong2 W2 = *(const ulonglong2*)(wg + 8);
  ulonglong2 W3 = *(const ulonglong2*)(wg + 12);
  ulonglong2 W4 = *(const ulonglong2*)(wg + 16);
  ulonglong2 W5 = *(const ulonglong2*)(wg + 20);
  ulonglong2 W6 = *(const ulonglong2*)(wg + 24);
  ulonglong2 W7 = *(const ulonglong2*)(wg + 28);
  ulonglong2 W8 = *(const ulonglong2*)(wg + 32);
  __syncthreads();
  short* outb = out + ((long)n * 512 + co) * 36;
#pragma unroll
  for (int k = 0; k < 9; k++) {
    int pos = slot + 4 * k;  // 0..35
    int py = pos / 6, px = pos - py * 6;
    const uint64_t* q = sIn + ((2 * py) * 14 + 2 * px) * 4 + 2 * h;
    int a00 = 0, a01 = 0, a10 = 0, a11 = 0;
    {
      ulonglong2 p0 = *(const ulonglong2*)(q + 0);
      ulonglong2 p1 = *(const ulonglong2*)(q + 4);
      ulonglong2 p2 = *(const ulonglong2*)(q + 8);
      ulonglong2 p3 = *(const ulonglong2*)(q + 12);
      ROWT(a00, a01, p0, p1, p2, p3, W0, W1, W2)
    }
    {
      const uint64_t* q1 = q + 56;
      ulonglong2 p0 = *(const ulonglong2*)(q1 + 0);
      ulonglong2 p1 = *(const ulonglong2*)(q1 + 4);
      ulonglong2 p2 = *(const ulonglong2*)(q1 + 8);
      ulonglong2 p3 = *(const ulonglong2*)(q1 + 12);
      ROWT(a00, a01, p0, p1, p2, p3, W3, W4, W5)
      ROWT(a10, a11, p0, p1, p2, p3, W0, W1, W2)
    }
    {
      const uint64_t* q2 = q + 112;
      ulonglong2 p0 = *(const ulonglong2*)(q2 + 0);
      ulonglong2 p1 = *(const ulonglong2*)(q2 + 4);
      ulonglong2 p2 = *(const ulonglong2*)(q2 + 8);
      ulonglong2 p3 = *(const ulonglong2*)(q2 + 12);
      ROWT(a00, a01, p0, p1, p2, p3, W6, W7, W8)
      ROWT(a10, a11, p0, p1, p2, p3, W3, W4, W5)
    }
    {
      const uint64_t* q3 = q + 168;
      ulonglong2 p0 = *(const ulonglong2*)(q3 + 0);
      ulonglong2 p1 = *(const ulonglong2*)(q3 + 4);
      ulonglong2 p2 = *(const ulonglong2*)(q3 + 8);
      ulonglong2 p3 = *(const ulonglong2*)(q3 + 12);
      ROWT(a10, a11, p0, p1, p2, p3, W6, W7, W8)
    }
    int t00 = a00 + __shfl_xor(a00, 32);
    int t01 = a01 + __shfl_xor(a01, 32);
    int t10 = a10 + __shfl_xor(a10, 32);
    int t11 = a11 + __shfl_xor(a11, 32);
    if (h == 0) {
      int dot = 2304 - 2 * min(min(t00, t01), min(t10, t11));
      outb[pos] = (short)dot;
    }
  }
}

// ---------------- binary fc ----------------

// fc0 + epilogue partials pp3[by][1024] so fc1 needs no reduce pass.
__global__ void fc_bin2_pp(const uint64_t* __restrict__ xp, const uint64_t* __restrict__ wp_t,
                           const float* __restrict__ cp, float* __restrict__ out,
                           double2* __restrict__ pp3, int O, int Wf) {
  __shared__ uint64_t xs[2][288], xz[2][288];
  int r0 = blockIdx.y * 2;
  for (int i = threadIdx.x; i < 2 * Wf; i += blockDim.x) {
    int rr = i / Wf, wd = i - rr * Wf;
    xs[rr][wd] = xp[(((long)(r0 + rr)) * Wf + wd) * 2];
    xz[rr][wd] = xp[(((long)(r0 + rr)) * Wf + wd) * 2 + 1];
  }
  __syncthreads();
  int o = blockIdx.x * blockDim.x + threadIdx.x;
  if (o >= O) return;
  int pc0 = 0, pc1 = 0, nz0 = 0, nz1 = 0;
  for (int wd = 0; wd < Wf; wd++) {
    uint64_t w = wp_t[(long)wd * O + o];
    uint64_t z0 = xz[0][wd], z1 = xz[1][wd];
    pc0 += __popcll((xs[0][wd] ^ w) & z0);
    pc1 += __popcll((xs[1][wd] ^ w) & z1);
    nz0 += __popcll(z0);
    nz1 += __popcll(z1);
  }
  float alpha = cp[0];
  int d0 = nz0 - 2 * pc0, d1 = nz1 - 2 * pc1;
  float v0 = (float)d0, v1 = (float)d1;
  v0 = d0 >= 0 ? v0 : alpha * v0;
  v1 = d1 >= 0 ? v1 : alpha * v1;
  out[(long)r0 * O + o] = v0;
  out[(long)(r0 + 1) * O + o] = v1;
  double dv0 = (double)v0, dv1 = (double)v1;
  pp3[(long)blockIdx.y * O + o] = make_double2(dv0 + dv1, dv0 * dv0 + dv1 * dv1);
}

// entire fc1 block in one kernel: block = row r.
__global__ void fc1_fused(const float* __restrict__ f1, const double2* __restrict__ pp3,
                          const float* __restrict__ g, const float* __restrict__ b,
                          const uint64_t* __restrict__ w4p, const float* __restrict__ cp,
                          const float* __restrict__ scale, float* __restrict__ out) {
  __shared__ uint64_t xs[16], xz[16];
  int r = blockIdx.x, t = threadIdx.x, lane = t & 63, wv = t >> 6;
  for (int it = 0; it < 4; it++) {
    int f = it * 256 + t;
    double s = 0.0, s2 = 0.0;
    for (int y = 0; y < 64; y++) {
      double2 p = pp3[(long)y * 1024 + f];
      s += p.x; s2 += p.y;
    }
    double m = s / 128.0;
    double v = s2 / 128.0 - m * m;
    double rs = 1.0 / sqrt(v + BN_EPS);
    double d = (double)f1[(long)r * 1024 + f] - m;  // exact lattice
    float xn = (float)(d * rs) * g[f] + b[f];
    uint64_t smk = __ballot(xn > 0.f);
    uint64_t nmk = __ballot(d != 0.0);
    if (lane == 0) { xs[it * 4 + wv] = smk; xz[it * 4 + wv] = nmk; }
  }
  __syncthreads();
  if (t < 10) {
    int pc = 0, nzc = 0;
    for (int wd = 0; wd < 16; wd++) {
      uint64_t nz = xz[wd];
      pc += __popcll((xs[wd] ^ w4p[wd * 10 + t]) & nz);
      nzc += __popcll(nz);
    }
    int dot = nzc - 2 * pc;
    float f = (float)dot;
    float alpha = cp[0];
    f = dot >= 0 ? f : alpha * f;
    out[(long)r * 10 + t] = f * scale[0];
  }
}

// ---------------- launch ----------------

extern "C" void kernel_launch(void* const* d_in, const int* in_sizes, int n_in,
                              void* d_out, int out_size, void* d_ws, size_t ws_size,
                              hipStream_t stream) {
  const float* x   = (const float*)d_in[0];
  const float* cg0 = (const float*)d_in[1];
  const float* cb0 = (const float*)d_in[2];
  const float* cw0 = (const float*)d_in[3];
  const float* cp0 = (const float*)d_in[4];
  const float* cg1 = (const float*)d_in[5];
  const float* cb1 = (const float*)d_in[6];
  const float* cw1 = (const float*)d_in[7];
  const float* cp1 = (const float*)d_in[8];
  const float* cg2 = (const float*)d_in[9];
  const float* cb2 = (const float*)d_in[10];
  const float* cw2 = (const float*)d_in[11];
  const float* cp2 = (const float*)d_in[12];
  const float* fg0 = (const float*)d_in[13];
  const float* fb0 = (const float*)d_in[14];
  const float* fw0 = (const float*)d_in[15];
  const float* fp0 = (const float*)d_in[16];
  const float* fg1 = (const float*)d_in[17];
  const float* fb1 = (const float*)d_in[18];
  const float* fw1 = (const float*)d_in[19];
  const float* fp1 = (const float*)d_in[20];
  const float* scl = (const float*)d_in[21];

  char* ws = (char*)d_ws;
  size_t off = 0;
  auto alloc = [&](size_t bytes) {
    size_t r = off;
    off += (bytes + 255) & ~(size_t)255;
    return r;
  };
  const int C1_OFF = 16, C2_OFF = 160;

  double*   sums  = (double*)(ws + alloc(18432L * 2 * sizeof(double)));   // fc0 stats
  double2*  stats = (double2*)(ws + alloc(512L * sizeof(double2)));       // C0..C2 channels
  double*   pplane= (double*)(ws + alloc(128L * 3 * 2 * sizeof(double)));
  double2*  pp1   = (double2*)(ws + alloc(2048L * 128 * sizeof(double2)));
  double2*  pp2   = (double2*)(ws + alloc(2048L * 64 * sizeof(double2)));
  double2*  pp3   = (double2*)(ws + alloc(64L * 1024 * sizeof(double2)));
  uint64_t* rows0 = (uint64_t*)(ws + alloc(128L * 3 * 64 * 8));
  uint32_t* wm1   = (uint32_t*)(ws + alloc(128L * 4));
  signed char* a1 = (signed char*)(ws + alloc(128L * 961 * 128));   // i8 dots, CL
  uint64_t* s1p   = (uint64_t*)(ws + alloc(128L * 961 * 2 * 8));
  uint64_t* w1p   = (uint64_t*)(ws + alloc(256L * 9 * 2 * 8));
  short*    a2    = (short*)(ws + alloc(128L * 196 * 256 * 2));     // i16 dots, CL
  uint64_t* s2p   = (uint64_t*)(ws + alloc(128L * 196 * 4 * 8));
  uint64_t* w2p   = (uint64_t*)(ws + alloc(512L * 9 * 4 * 8));
  short*    a3    = (short*)(ws + alloc(128L * 512 * 36 * 2));      // i16 dots, CM
  uint64_t* s3p   = (uint64_t*)(ws + alloc(128L * 288 * 2 * 8));
  uint64_t* w3p   = (uint64_t*)(ws + alloc(1024L * 288 * 8));       // transposed [288][1024]
  float*    f1    = (float*)(ws + alloc(128L * 1024 * 4));
  uint64_t* w4p   = (uint64_t*)(ws + alloc(10L * 16 * 8));          // transposed [16][10]

  const int B = 256;

  // 1: all weight packs + zero of fc0 atomic region (input-independent)
  pack_weights_all<<<dim3(9456), B, 0, stream>>>(cw0, cw1, cw2, fw0, fw1,
                                                 wm1, w1p, w2p, w3p, w4p,
                                                 sums, 36864);

  // ---- block 0 ----
  reduce_plane_p<<<dim3(3, 128), B, 0, stream>>>(x, pplane, 3, 4096);
  pack_bits_c1_f<<<dim3(768), B, 0, stream>>>(x, pplane, cg0, cb0, rows0, 24576);
  conv1_pool3_i8<<<dim3(16, 128), B, 0, stream>>>(rows0, wm1, cp0, a1, pp1);

  // ---- block 1 ----
  finalize_pp1<<<dim3(128), B, 0, stream>>>(pp1, stats + C1_OFF, 128, 2048, 123008.0);
  pack_cl_i8<<<dim3(7688), B, 0, stream>>>(a1, stats + C1_OFF, cg1, cb1, cp0, s1p, 128, 246016L, 1);
  // conv2 split into two half-batch dispatches (diagnostic: unmask kernels >=40us)
  convp_carry_i16<2, 31, 14, 4><<<dim3(16, 64), B, 0, stream>>>(s1p, w1p, cp1, a2, pp2, 256, 0);
  convp_carry_i16<2, 31, 14, 4><<<dim3(16, 64), B, 0, stream>>>(s1p, w1p, cp1, a2, pp2, 256, 64);

  // ---- block 2 ----
  finalize_pp2<<<dim3(256), B, 0, stream>>>(pp2, stats + C2_OFF, 25088.0);
  pack_cl_i16<<<dim3(3136), B, 0, stream>>>(a2, stats + C2_OFF, cg2, cb2, cp1, s2p, 256, 100352L, 2);
  convs3_i16<<<dim3(16, 64), B, 0, stream>>>(s2p, w2p, a3, 0);
  convs3_i16<<<dim3(16, 64), B, 0, stream>>>(s2p, w2p, a3, 64);

  // ---- fc 0 ----
  reduce_cols2_i16<<<dim3(72, 8), B, 0, stream>>>(a3, cp2, sums, 128, 18432, 16);
  pack_nz_st_i16<<<dim3(1152), B, 0, stream>>>(a3, sums, fg0, fb0, cp2, s3p, 128, 18432);
  fc_bin2_pp<<<dim3(4, 64), B, 0, stream>>>(s3p, w3p, fp0, f1, pp3, 1024, 288);

  // ---- fc 1 (single fused kernel) ----
  fc1_fused<<<dim3(128), B, 0, stream>>>(f1, pp3, fg1, fb1, w4p, fp1, scl, (float*)d_out);
}